// Round 6
// baseline (448.780 us; speedup 1.0000x reference)
//
#include <hip/hip_runtime.h>
#include <math.h>

// Dynamic_Loss on MI355X.
// Shapes: logit/ema_prob [8,20,512,512] f32, real_labels [8,512,512] i32,
// ema_thresh/moving_prob_avg [20] f32. Output: scalar f32.
//
// Factorization: loss = sum_c (1-new_mpa[c]) * Lsum[c] / n_valid, where
// Lsum[c] = sum over valid pixels with ema-class c of (lse - logit[c]).
// One streaming pass accumulates 61 scalars; a tiny kernel finishes.
// ws layout (floats): [0..19] score sums, [20..39] counts, [40..59] loss sums,
// [60] valid count.
//
// Round 6: float4 x high-occupancy — the one untested cell. Cross-round:
// BW tracks (transaction width x resident waves); per-wave inflight depth
// is fixed by the compiled rhythm (R3 DMA null), and all high-occ attempts
// so far also dropped to float2 (R2/R4). This round keeps R0's exact
// structure (4 px/thread float4, split ema/logit passes, 2048 blocks) but
// minimizes live state so it fits __launch_bounds__(256,8) (VGPR cap 64):
// rl and esel are stashed in LDS across passes; pass-2 live set ~24 regs.
// Spill tripwire: WRITE_SIZE must stay ~512 KB.
//
// Semantics (absmax 0.0 lineage R1-R5):
//   esel/earg = for rl<15: running (ema max over c<15, argmax); for rl>=15:
//   (ema[rl], rl); for IGN: (ema[0], 0). xsel = logit at earg. For rl>=15
//   the captured logit serves BOTH the score gather and loss gather.

#define PASTC 15
#define NCC   20
#define IGN   255
#define HW2   262144          // 512*512 = 2^18
#define ALPHAF 0.99f

__global__ __launch_bounds__(256, 8) void dl_main(
    const float* __restrict__ logit,
    const float* __restrict__ ema,
    const float* __restrict__ thresh,
    const int*   __restrict__ real,
    float*       __restrict__ ws)
{
    __shared__ float  s_acc[61];
    __shared__ float  s_thr[NCC];
    __shared__ int4   s_rl[256];     // stash real labels across passes
    __shared__ float4 s_es[256];     // stash esel across pass 2

    const int tid = threadIdx.x;
    if (tid < 61) s_acc[tid] = 0.0f;
    if (tid < NCC) s_thr[tid] = thresh[tid];
    __syncthreads();

    const int t  = blockIdx.x * 256 + tid;
    const int p0 = t << 2;                       // 4 pixels per thread
    const int b  = p0 >> 18;                     // batch
    const int s  = p0 & (HW2 - 1);               // spatial offset
    const size_t base = (((size_t)(b * NCC)) << 18) + (size_t)s;
    const float* eb = ema   + base;
    const float* lb = logit + base;

    const int4 rl4 = *reinterpret_cast<const int4*>(real + p0);
    s_rl[tid] = rl4;                             // own slot only; no barrier
    const int rl[4] = {rl4.x, rl4.y, rl4.z, rl4.w};

    int   cap[4], earg[4];
    float esel[4];
#pragma unroll
    for (int j = 0; j < 4; ++j) {
        cap[j]  = (rl[j] == IGN) ? 0 : (rl[j] >= PASTC ? rl[j] : -1);
        esel[j] = -INFINITY; earg[j] = 0;
    }

    // ---------- pass 1: ema (argmax over c<15 + capture channels) ----------
#pragma unroll
    for (int c = 0; c < PASTC; ++c) {
        const float4 v = *reinterpret_cast<const float4*>(eb + ((size_t)c << 18));
        const float ev[4] = {v.x, v.y, v.z, v.w};
#pragma unroll
        for (int j = 0; j < 4; ++j) {
            const bool upd = (cap[j] < 0) ? (ev[j] > esel[j]) : (c == cap[j]);
            esel[j] = upd ? ev[j] : esel[j];
            earg[j] = upd ? c     : earg[j];
        }
    }
#pragma unroll
    for (int c = PASTC; c < NCC; ++c) {          // capture-only channels
        const float4 v = *reinterpret_cast<const float4*>(eb + ((size_t)c << 18));
        const float ev[4] = {v.x, v.y, v.z, v.w};
#pragma unroll
        for (int j = 0; j < 4; ++j) {
            const bool upd = (c == cap[j]);
            esel[j] = upd ? ev[j] : esel[j];
            earg[j] = upd ? c     : earg[j];
        }
    }
    s_es[tid] = make_float4(esel[0], esel[1], esel[2], esel[3]);
    // earg now == gather channel for ALL pixels. cap/esel/rl dead in regs.

    // ---------- pass 2: logit (sum exp + argmax<15 + capture at earg) ------
    float se[4], x_m15[4], xsel[4];
    int   arg15[4];
#pragma unroll
    for (int j = 0; j < 4; ++j) {
        se[j] = 0.0f; x_m15[j] = -INFINITY; xsel[j] = 0.0f; arg15[j] = 0;
    }
#pragma unroll
    for (int c = 0; c < PASTC; ++c) {
        const float4 v = *reinterpret_cast<const float4*>(lb + ((size_t)c << 18));
        const float xv[4] = {v.x, v.y, v.z, v.w};
#pragma unroll
        for (int j = 0; j < 4; ++j) {
            const float x = xv[j];
            se[j] += __expf(x);
            const bool gl = x > x_m15[j];        // first-max ties (jnp.argmax)
            x_m15[j] = gl ? x : x_m15[j];
            arg15[j] = gl ? c : arg15[j];
            xsel[j]  = (c == earg[j]) ? x : xsel[j];
        }
    }
#pragma unroll
    for (int c = PASTC; c < NCC; ++c) {
        const float4 v = *reinterpret_cast<const float4*>(lb + ((size_t)c << 18));
        const float xv[4] = {v.x, v.y, v.z, v.w};
#pragma unroll
        for (int j = 0; j < 4; ++j) {
            const float x = xv[j];
            se[j] += __expf(x);
            xsel[j] = (c == earg[j]) ? x : xsel[j];
        }
    }

    // ---------- per-pixel epilogue -> LDS bins ----------
    const int4   rr4 = s_rl[tid];
    const float4 ee4 = s_es[tid];
    const int   rrl[4] = {rr4.x, rr4.y, rr4.z, rr4.w};
    const float ees[4] = {ee4.x, ee4.y, ee4.z, ee4.w};

    float vcnt = 0.0f;
#pragma unroll
    for (int j = 0; j < 4; ++j) {
        const float lse = __logf(se[j]);         // ln(sum exp)
        if (rrl[j] != IGN) {
            const int   lab  = (rrl[j] >= PASTC) ? rrl[j] : arg15[j]; // [0,19]
            const float sval = (rrl[j] >= PASTC) ? xsel[j] : x_m15[j];
            const float prob = __expf(sval - lse);
            atomicAdd(&s_acc[lab], prob);
            atomicAdd(&s_acc[20 + lab], 1.0f);
        }
        const int  el    = (rrl[j] >= PASTC) ? rrl[j] : earg[j]; // 255 stays 255
        const float th   = s_thr[el < NCC ? el : (NCC - 1)];
        const bool valid = (el < NCC) && (ees[j] >= th);
        if (valid) {
            atomicAdd(&s_acc[40 + el], lse - xsel[j]);
        }
        const unsigned long long bm = __ballot(valid);
        if ((tid & 63) == 0) vcnt += (float)__popcll(bm);
    }
    if ((tid & 63) == 0) atomicAdd(&s_acc[60], vcnt);

    __syncthreads();
    if (tid < 61) atomicAdd(&ws[tid], s_acc[tid]);
}

__global__ void dl_final(const float* __restrict__ ws,
                         const float* __restrict__ mpa,
                         float*       __restrict__ out)
{
    if (threadIdx.x == 0 && blockIdx.x == 0) {
        float acc = 0.0f;
        for (int c = 0; c < NCC; ++c) {
            const float ssum = ws[c];
            const float cnt  = ws[20 + c];
            const float lsum = ws[40 + c];
            const float m    = mpa[c];
            const float mean = ssum / fmaxf(cnt, 1.0f);
            const float nm   = (cnt > 0.0f)
                                 ? ((m == -1.0f) ? mean
                                                 : (1.0f - ALPHAF) * mean + ALPHAF * m)
                                 : m;
            acc += lsum * (1.0f - nm);
        }
        out[0] = acc / ws[60];
    }
}

extern "C" void kernel_launch(void* const* d_in, const int* in_sizes, int n_in,
                              void* d_out, int out_size, void* d_ws, size_t ws_size,
                              hipStream_t stream) {
    const float* logit  = (const float*)d_in[0];
    const float* ema    = (const float*)d_in[1];
    const float* thresh = (const float*)d_in[2];
    const int*   real   = (const int*)d_in[3];
    const float* mpa    = (const float*)d_in[4];
    float* out = (float*)d_out;
    float* ws  = (float*)d_ws;

    // ws is re-poisoned to 0xAA before every timed launch; zero the 61 bins.
    hipMemsetAsync(ws, 0, 64 * sizeof(float), stream);

    // 2,097,152 pixels / 4 per thread / 256 per block = 2048 blocks (exact)
    dl_main<<<2048, 256, 0, stream>>>(logit, ema, thresh, real, ws);
    dl_final<<<1, 64, 0, stream>>>(ws, mpa, out);
}

// Round 8
// 405.377 us; speedup vs baseline: 1.1071x; 1.1071x over previous
//
#include <hip/hip_runtime.h>
#include <math.h>

// Dynamic_Loss on MI355X.
// Shapes: logit/ema_prob [8,20,512,512] f32, real_labels [8,512,512] i32,
// ema_thresh/moving_prob_avg [20] f32. Output: scalar f32.
//
// Factorization: loss = sum_c (1-new_mpa[c]) * Lsum[c] / n_valid, where
// Lsum[c] = sum over valid pixels with ema-class c of (lse - logit[c]).
// One streaming pass accumulates 61 scalars; a tiny kernel finishes.
// ws layout (floats): [0..19] score sums, [20..39] counts, [40..59] loss sums,
// [60] valid count.
//
// Round 8 = Round 7 with the compile fix: __builtin_nontemporal_load needs a
// clang ext_vector_type, not HIP_vector_type float4.
//
// Cache-policy probe: useful-READ throughput is pinned at ~2.7 TB/s across
// occupancy 19..79% (null), per-wave depth x8 via DMA (null), bursts
// 2..16KB (null); only float4 vs float2 width matters. R0 sits exactly at
// 344MB/2.7TB/s. Currently HBM serves 168MB @1.35TB/s and L3 the other
// ~176MB @1.35TB/s (working set 344MB > 256MB L3 -> LRU thrash, both lanes
// slow). This round: NONTEMPORAL loads on logit only -> L3 retains
// ema+real (176MB, fits), logit streams from HBM. If reads are
// request-side capped this is flat and R0 is the roofline; if the cap is
// L3-miss arbitration, this unlocks. Body = known-good split-pass
// 4px/float4 (absmax 0.0 lineage), NO launch bounds (R2/R6: bounds(256,8)
// => compiler picks VGPR=32 and spills), state in registers.
//
// Semantics (absmax 0.0 lineage R1-R6):
//   esel/earg = for rl<15: running (ema max over c<15, argmax); for rl>=15:
//   (ema[rl], rl); for IGN: (ema[0], 0). xsel = logit at earg. For rl>=15
//   the captured logit serves BOTH the score gather and loss gather.

#define PASTC 15
#define NCC   20
#define IGN   255
#define HW2   262144          // 512*512 = 2^18
#define ALPHAF 0.99f

typedef float fx4 __attribute__((ext_vector_type(4)));

__global__ void dl_main(
    const float* __restrict__ logit,
    const float* __restrict__ ema,
    const float* __restrict__ thresh,
    const int*   __restrict__ real,
    float*       __restrict__ ws)
{
    __shared__ float s_acc[61];
    __shared__ float s_thr[NCC];
    const int tid = threadIdx.x;
    if (tid < 61) s_acc[tid] = 0.0f;
    if (tid < NCC) s_thr[tid] = thresh[tid];
    __syncthreads();

    const int t  = blockIdx.x * 256 + tid;
    const int p0 = t << 2;                       // 4 pixels per thread
    const int b  = p0 >> 18;                     // batch
    const int s  = p0 & (HW2 - 1);               // spatial offset
    const size_t base = (((size_t)(b * NCC)) << 18) + (size_t)s;
    const float* eb = ema   + base;
    const float* lb = logit + base;

    const int4 rl4 = *reinterpret_cast<const int4*>(real + p0);
    const int rl[4] = {rl4.x, rl4.y, rl4.z, rl4.w};

    int   cap[4], earg[4];
    float esel[4];
#pragma unroll
    for (int j = 0; j < 4; ++j) {
        cap[j]  = (rl[j] == IGN) ? 0 : (rl[j] >= PASTC ? rl[j] : -1);
        esel[j] = -INFINITY; earg[j] = 0;
    }

    // ---------- pass 1: ema (argmax over c<15 + capture channels) ----------
    // ema stays CACHEABLE: with logit marked nontemporal, ema+real (176MB)
    // fit in the 256MB L3 and are retained across iterations.
#pragma unroll
    for (int c = 0; c < PASTC; ++c) {
        const float4 v = *reinterpret_cast<const float4*>(eb + ((size_t)c << 18));
        const float ev[4] = {v.x, v.y, v.z, v.w};
#pragma unroll
        for (int j = 0; j < 4; ++j) {
            const bool upd = (cap[j] < 0) ? (ev[j] > esel[j]) : (c == cap[j]);
            esel[j] = upd ? ev[j] : esel[j];
            earg[j] = upd ? c     : earg[j];
        }
    }
#pragma unroll
    for (int c = PASTC; c < NCC; ++c) {          // capture-only channels
        const float4 v = *reinterpret_cast<const float4*>(eb + ((size_t)c << 18));
        const float ev[4] = {v.x, v.y, v.z, v.w};
#pragma unroll
        for (int j = 0; j < 4; ++j) {
            const bool upd = (c == cap[j]);
            esel[j] = upd ? ev[j] : esel[j];
            earg[j] = upd ? c     : earg[j];
        }
    }
    // earg now == gather channel for ALL pixels (rl<15: ema argmax;
    // rl>=15: rl; IGN: 0). cap[] is dead from here.

    // ---------- pass 2: logit, NONTEMPORAL (stream once, don't pollute L3) -
    float se[4], x_m15[4], xsel[4];
    int   arg15[4];
#pragma unroll
    for (int j = 0; j < 4; ++j) {
        se[j] = 0.0f; x_m15[j] = -INFINITY; xsel[j] = 0.0f; arg15[j] = 0;
    }
#pragma unroll
    for (int c = 0; c < PASTC; ++c) {
        const fx4 v = __builtin_nontemporal_load(
            reinterpret_cast<const fx4*>(lb + ((size_t)c << 18)));
        const float xv[4] = {v.x, v.y, v.z, v.w};
#pragma unroll
        for (int j = 0; j < 4; ++j) {
            const float x = xv[j];
            se[j] += __expf(x);
            const bool gl = x > x_m15[j];        // first-max ties (jnp.argmax)
            x_m15[j] = gl ? x : x_m15[j];
            arg15[j] = gl ? c : arg15[j];
            xsel[j]  = (c == earg[j]) ? x : xsel[j];
        }
    }
#pragma unroll
    for (int c = PASTC; c < NCC; ++c) {
        const fx4 v = __builtin_nontemporal_load(
            reinterpret_cast<const fx4*>(lb + ((size_t)c << 18)));
        const float xv[4] = {v.x, v.y, v.z, v.w};
#pragma unroll
        for (int j = 0; j < 4; ++j) {
            const float x = xv[j];
            se[j] += __expf(x);
            xsel[j] = (c == earg[j]) ? x : xsel[j];
        }
    }

    // ---------- per-pixel epilogue -> LDS bins ----------
    float vcnt = 0.0f;
#pragma unroll
    for (int j = 0; j < 4; ++j) {
        const float lse = __logf(se[j]);         // ln(sum exp)
        if (rl[j] != IGN) {
            const int   lab  = (rl[j] >= PASTC) ? rl[j] : arg15[j];  // [0,19]
            const float sval = (rl[j] >= PASTC) ? xsel[j] : x_m15[j];
            const float prob = __expf(sval - lse);
            atomicAdd(&s_acc[lab], prob);
            atomicAdd(&s_acc[20 + lab], 1.0f);
        }
        const int  el    = (rl[j] >= PASTC) ? rl[j] : earg[j];  // 255 stays 255
        const float th   = s_thr[el < NCC ? el : (NCC - 1)];
        const bool valid = (el < NCC) && (esel[j] >= th);
        if (valid) {
            atomicAdd(&s_acc[40 + el], lse - xsel[j]);
        }
        const unsigned long long bm = __ballot(valid);
        if ((tid & 63) == 0) vcnt += (float)__popcll(bm);
    }
    if ((tid & 63) == 0) atomicAdd(&s_acc[60], vcnt);

    __syncthreads();
    if (tid < 61) atomicAdd(&ws[tid], s_acc[tid]);
}

__global__ void dl_final(const float* __restrict__ ws,
                         const float* __restrict__ mpa,
                         float*       __restrict__ out)
{
    if (threadIdx.x == 0 && blockIdx.x == 0) {
        float acc = 0.0f;
        for (int c = 0; c < NCC; ++c) {
            const float ssum = ws[c];
            const float cnt  = ws[20 + c];
            const float lsum = ws[40 + c];
            const float m    = mpa[c];
            const float mean = ssum / fmaxf(cnt, 1.0f);
            const float nm   = (cnt > 0.0f)
                                 ? ((m == -1.0f) ? mean
                                                 : (1.0f - ALPHAF) * mean + ALPHAF * m)
                                 : m;
            acc += lsum * (1.0f - nm);
        }
        out[0] = acc / ws[60];
    }
}

extern "C" void kernel_launch(void* const* d_in, const int* in_sizes, int n_in,
                              void* d_out, int out_size, void* d_ws, size_t ws_size,
                              hipStream_t stream) {
    const float* logit  = (const float*)d_in[0];
    const float* ema    = (const float*)d_in[1];
    const float* thresh = (const float*)d_in[2];
    const int*   real   = (const int*)d_in[3];
    const float* mpa    = (const float*)d_in[4];
    float* out = (float*)d_out;
    float* ws  = (float*)d_ws;

    // ws is re-poisoned to 0xAA before every timed launch; zero the 61 bins.
    hipMemsetAsync(ws, 0, 64 * sizeof(float), stream);

    // 2,097,152 pixels / 4 per thread / 256 per block = 2048 blocks (exact)
    dl_main<<<2048, 256, 0, stream>>>(logit, ema, thresh, real, ws);
    dl_final<<<1, 64, 0, stream>>>(ws, mpa, out);
}